// Round 11
// baseline (41449.826 us; speedup 1.0000x reference)
//
#include <hip/hip_runtime.h>
#include <hip/hip_bf16.h>
#include <stdint.h>

// Neural ODE (RK4, 32 steps) over a 5-layer MLP, B=32768, VAR_DIM=50 (pad 64).
// bf16 MFMA GEMMs (16x16x32), fp32 accum, fp32 state y.
// concat(h,t) @ W == h @ W[:K] + (b + t*W[K]) -> time column folded into bias.
// r10: gemm256 = exact r7 loop (best known, 35.17ms) with B routed directly
//      global(L2)->VGPR: W is 2MB, L2-resident on every XCD. Deletes Bs LDS
//      (128->64KB), 4 stage gloads and 8 ds_reads per wave per tile
//      (DS pipe 2304->1536 cyc/tile). B frag loads issued 1-2 quads before
//      use; compiler inserts exact per-use vmcnt. Mid-tile wait is a counted
//      vmcnt(4) (keeps the 4 fresh B loads in flight).

typedef __bf16 bf16_t;
typedef bf16_t bf16x8 __attribute__((ext_vector_type(8)));
typedef float  f32x4  __attribute__((ext_vector_type(4)));

#define DEVI static __device__ __forceinline__

DEVI void gload_lds16(const bf16_t* gsrc, bf16_t* ldst) {
  __builtin_amdgcn_global_load_lds(
      (const __attribute__((address_space(1))) uint32_t*)gsrc,
      (__attribute__((address_space(3))) uint32_t*)ldst,
      16, 0, 0);
}

// ---------------------------------------------------------------------------
// 256x256 tile, BK=64, 8 waves (2Mx4N, 128x64 each).
// A: double-buffered LDS (st-swizzled, linear gload_lds dest + pre-swizzled
//    global source col; same XOR on ds_read).
// B: direct global->VGPR fragments (no LDS), reloaded per tile into the same
//    registers after their last MFMA use.
// Per K-tile T (buf = T&1):
//   stage A(T+1) ; read ah1 ; q00 q01 q10 ; issue bh0(T+1)
//   vmcnt(4) [drains stage, keeps bh0 flying] ; barrier ; read ah0(T+1) ; q11
//   issue bh1(T+1)
// ---------------------------------------------------------------------------
template<int K>
__global__ __launch_bounds__(512, 2) void gemm256(
    const bf16_t* __restrict__ A,     // M x K row-major
    const bf16_t* __restrict__ BT,    // N x K row-major (pre-transposed W)
    const float* __restrict__ bias,
    const float* __restrict__ wtime,
    float t,
    bf16_t* __restrict__ C, int ldc,
    int M, int N)
{
  constexpr int NT = K / 64;          // K-tiles
  static_assert(NT >= 3, "pipeline needs >=3 K-tiles");

  __shared__ __align__(16) bf16_t As[2][256][64];   // 64 KiB

  const int tid  = threadIdx.x;
  const int wave = tid >> 6;
  const int lane = tid & 63;
  const int wr = wave >> 2;           // 0..1 -> 128-row half
  const int wc = wave & 3;            // 0..3 -> 64-col strip

  // T1: XCD-aware bijective swizzle (gridDim.x % 8 == 0 by construction)
  int wg = blockIdx.x;
  {
    const int cpx = gridDim.x >> 3;
    wg = (wg & 7) * cpx + (wg >> 3);
  }
  const int nbn = N >> 8;
  const int bm = (wg / nbn) << 8;
  const int bn = (wg % nbn) << 8;

  // A staging: dest row r = [buf*256 + h*128 +] wave*8 + (lane>>3)
  //   -> r&4 = lane&32-bit, r&8 = wave&1.  Pre-swizzled SOURCE col.
  const int srow = lane >> 3;
  const int scol = ((lane & 7) << 3) ^ ((lane & 32) >> 1) ^ ((wave & 1) << 5);
  const bf16_t* aS = A + (size_t)(bm + wave * 8 + srow) * K + scol;
  bf16_t* aD = &As[0][0][0] + wave * 8 * 64;   // wave-uniform LDS base

  auto stageTile = [&](int kt) {   // A only: 4 gloads per wave
    const int buf = kt & 1;
#pragma unroll
    for (int h = 0; h < 2; ++h) {
      const bf16_t* src = aS + (size_t)(h * 128) * K + kt * 64;
      bf16_t*       dst = aD + (buf * 256 + h * 128) * 64;
      gload_lds16(src,                  dst);
      gload_lds16(src + (size_t)64 * K, dst + 64 * 64);
    }
  };

  const int fr = lane & 15;
  const int fq = lane >> 4;
  const int rsw = ((fr & 4) << 3) ^ ((fr & 8) << 3);   // byte-XOR from row bits

  bf16x8 ah0[8], ah1[8];   // A frags, mh=0 / mh=1  [m*2+kk]
  bf16x8 bh0[4], bh1[4];   // B frags, nh=0 / nh=1  [n*2+kk]  (global-fed)
  f32x4  acc[8][4] = {};

  auto lda_into = [&](bf16x8 (&dst)[8], int buf, int mh) {
    const char* base = (const char*)&As[buf][0][0];
#pragma unroll
    for (int m = 0; m < 4; ++m)
#pragma unroll
      for (int kk = 0; kk < 2; ++kk) {
        int r  = wr * 128 + (mh * 4 + m) * 16 + fr;
        int cb = (kk * 64 + fq * 16) ^ rsw;
        dst[m * 2 + kk] = *(const bf16x8*)(base + r * 128 + cb);
      }
  };
  // B fragment straight from global (L2-resident W): row = output col,
  // elems k = kt*64 + kk*32 + fq*8 (16B aligned).
  auto ldbg = [&](bf16x8 (&dst)[4], int kt, int nh) {
#pragma unroll
    for (int n = 0; n < 2; ++n)
#pragma unroll
      for (int kk = 0; kk < 2; ++kk) {
        const bf16_t* p = BT + (size_t)(bn + wc * 64 + nh * 32 + n * 16 + fr) * K
                             + kt * 64 + kk * 32 + fq * 8;
        dst[n * 2 + kk] = *(const bf16x8*)p;
      }
  };
  auto mma_quad = [&](bf16x8 (&a)[8], bf16x8 (&b)[4], int mh, int nh) {
    __builtin_amdgcn_s_setprio(1);
#pragma unroll
    for (int m = 0; m < 4; ++m)
#pragma unroll
      for (int n = 0; n < 2; ++n)
#pragma unroll
        for (int kk = 0; kk < 2; ++kk)
          acc[mh * 4 + m][nh * 2 + n] = __builtin_amdgcn_mfma_f32_16x16x32_bf16(
              a[m * 2 + kk], b[n * 2 + kk],
              acc[mh * 4 + m][nh * 2 + n], 0, 0, 0);
    __builtin_amdgcn_s_setprio(0);
  };

  // prologue: stage A(0); issue B frags for tile0; drain stage only.
  stageTile(0);                       // 4 gloads
  ldbg(bh0, 0, 0);                    // 4 globals
  ldbg(bh1, 0, 1);                    // 4 globals
  asm volatile("s_waitcnt vmcnt(8)" ::: "memory");   // stage(0) done, B flying
  __builtin_amdgcn_s_barrier();
  lda_into(ah0, 0, 0);

  for (int t2 = 0; t2 < NT; ++t2) {
    const int buf = t2 & 1;
    if (t2 + 1 < NT) stageTile(t2 + 1);   // 4 gloads -> other buffer
    lda_into(ah1, buf, 1);                // 8 ds_reads (this tile, mh=1)
    mma_quad(ah0, bh0, 0, 0);             // q00 (compiler waits bh0/ah0)
    mma_quad(ah0, bh1, 0, 1);             // q01
    mma_quad(ah1, bh0, 1, 0);             // q10 (last read of bh0)
    if (t2 + 1 < NT) {
      ldbg(bh0, t2 + 1, 0);               // reload bh0 for T+1 (4 globals)
      asm volatile("s_waitcnt vmcnt(4)" ::: "memory");  // stage(T+1) done; bh0 flying
      __builtin_amdgcn_s_barrier();                     // all waves staged
      lda_into(ah0, buf ^ 1, 0);          // T+1 frags overlap q11 MFMAs
    }
    mma_quad(ah1, bh1, 1, 1);             // q11 (operands in regs; last bh1 use)
    if (t2 + 1 < NT) ldbg(bh1, t2 + 1, 1);  // reload bh1 for T+1
  }

  // epilogue: bias(t) + ReLU, bf16 out
#pragma unroll
  for (int n = 0; n < 4; ++n) {
    const int gcol = bn + wc * 64 + n * 16 + fr;
    const float bv = bias[gcol] + t * wtime[gcol];
#pragma unroll
    for (int m = 0; m < 8; ++m) {
      const int grow0 = bm + wr * 128 + m * 16 + (fq << 2);
#pragma unroll
      for (int r = 0; r < 4; ++r) {
        float v = acc[m][n][r] + bv;
        v = v > 0.0f ? v : 0.0f;
        C[(size_t)(grow0 + r) * ldc + gcol] = (bf16_t)v;
      }
    }
  }
}

// ---------------------------------------------------------------------------
// 128^2 kernel for layer 0 (K=64), full bank-spread swizzle.
// ---------------------------------------------------------------------------
template<int BM, int BN, int BK, int WROWS, int WCOLS, bool RELU, bool OUT_BF16>
__global__ __launch_bounds__(256) void gemm_bt(
    const bf16_t* __restrict__ A, int lda,
    const bf16_t* __restrict__ BT,
    const float* __restrict__ bias,
    const float* __restrict__ wtime,
    float t,
    void* __restrict__ Cv, int ldc,
    int M, int K)
{
  static_assert(BK == 64, "swizzle assumes BK=64");
  constexpr int MR  = BM / WROWS / 16;
  constexpr int NR  = BN / WCOLS / 16;
  constexpr int TPR = BK / 8;        // 8
  constexpr int RPW = 64 / TPR;      // 8
  constexpr int RPL = 4 * RPW;       // 32
  static_assert(BM % RPL == 0 && BN % RPL == 0, "tile staging mismatch");

  __shared__ bf16_t As[BM][BK];
  __shared__ bf16_t Bs[BN][BK];

  const int tid  = threadIdx.x;
  const int wave = tid >> 6;
  const int lane = tid & 63;
  const int wr = wave / WCOLS;
  const int wc = wave % WCOLS;
  const int bm = blockIdx.x * BM;
  const int bn = blockIdx.y * BN;
  const int lrow = lane >> 3;
  const int lcol = (((lane & 7) << 3) ^ ((lane & 32) >> 1) ^ ((wave & 1) << 5));

  const int fr = lane & 15;
  const int fq = lane >> 4;
  const int esw = ((fr & 4) << 2) ^ ((fr & 8) << 2);  // element-XOR from row bits

  f32x4 acc[MR][NR] = {};

  for (int k0 = 0; k0 < K; k0 += BK) {
#pragma unroll
    for (int i = 0; i < BM / RPL; ++i) {
      const int rb = i * RPL + wave * RPW;
      gload_lds16(&A[(size_t)(bm + rb + lrow) * lda + k0 + lcol], &As[rb][0]);
    }
#pragma unroll
    for (int i = 0; i < BN / RPL; ++i) {
      const int rb = i * RPL + wave * RPW;
      gload_lds16(&BT[(size_t)(bn + rb + lrow) * K + k0 + lcol], &Bs[rb][0]);
    }
    __syncthreads();
#pragma unroll
    for (int kk = 0; kk < BK / 32; ++kk) {
      bf16x8 af[MR], bfr[NR];
      const int ecol = (kk * 32 + fq * 8) ^ esw;
#pragma unroll
      for (int m = 0; m < MR; ++m)
        af[m] = *(const bf16x8*)&As[wr * (BM / WROWS) + m * 16 + fr][ecol];
#pragma unroll
      for (int n = 0; n < NR; ++n)
        bfr[n] = *(const bf16x8*)&Bs[wc * (BN / WCOLS) + n * 16 + fr][ecol];
#pragma unroll
      for (int m = 0; m < MR; ++m)
#pragma unroll
        for (int n = 0; n < NR; ++n)
          acc[m][n] = __builtin_amdgcn_mfma_f32_16x16x32_bf16(
              af[m], bfr[n], acc[m][n], 0, 0, 0);
    }
    __syncthreads();
  }

#pragma unroll
  for (int n = 0; n < NR; ++n) {
    const int gcol = bn + wc * (BN / WCOLS) + n * 16 + fr;
    const float bv = bias[gcol] + t * wtime[gcol];
#pragma unroll
    for (int m = 0; m < MR; ++m) {
      const int grow0 = bm + wr * (BM / WROWS) + m * 16 + (fq << 2);
#pragma unroll
      for (int r = 0; r < 4; ++r) {
        float v = acc[m][n][r] + bv;
        if (RELU) v = v > 0.0f ? v : 0.0f;
        if constexpr (OUT_BF16)
          ((bf16_t*)Cv)[(size_t)(grow0 + r) * ldc + gcol] = (bf16_t)v;
        else
          ((float*)Cv)[(size_t)(grow0 + r) * ldc + gcol] = v;
      }
    }
  }
}

// ---------------------------------------------------------------------------
// Layer 4 (N=64, K=1024) with RK4 combine fused into the epilogue.
// BM=64, BN=64, 4 waves (2x2) -> 512 blocks = 2 blocks/CU.  Swizzled LDS.
// ---------------------------------------------------------------------------
__global__ __launch_bounds__(256) void gemm_l4_rk4(
    const bf16_t* __restrict__ A, int lda,
    const bf16_t* __restrict__ BT,
    const float* __restrict__ bias,
    const float* __restrict__ wtime,
    float t,
    float* __restrict__ y, float* __restrict__ accb,
    bf16_t* __restrict__ ybf,
    float ca, float cs, int mode,
    int M, int K)
{
  constexpr int BM = 64, BN = 64, BK = 64;
  constexpr int MR = 2, NR = 2;

  __shared__ bf16_t As[BM][BK];
  __shared__ bf16_t Bs[BN][BK];

  const int tid  = threadIdx.x;
  const int wave = tid >> 6;
  const int lane = tid & 63;
  const int wr = wave >> 1;
  const int wc = wave & 1;
  const int bm = blockIdx.x * BM;
  const int lrow = lane >> 3;
  const int lcol = (((lane & 7) << 3) ^ ((lane & 32) >> 1) ^ ((wave & 1) << 5));

  const int fr = lane & 15;
  const int fq = lane >> 4;
  const int esw = ((fr & 4) << 2) ^ ((fr & 8) << 2);

  f32x4 acc[MR][NR] = {};

  for (int k0 = 0; k0 < K; k0 += BK) {
#pragma unroll
    for (int i = 0; i < 2; ++i) {
      const int rb = i * 32 + wave * 8;
      gload_lds16(&A[(size_t)(bm + rb + lrow) * lda + k0 + lcol], &As[rb][0]);
    }
#pragma unroll
    for (int i = 0; i < 2; ++i) {
      const int rb = i * 32 + wave * 8;
      gload_lds16(&BT[(size_t)(rb + lrow) * K + k0 + lcol], &Bs[rb][0]);
    }
    __syncthreads();
#pragma unroll
    for (int kk = 0; kk < 2; ++kk) {
      bf16x8 af[MR], bfr[NR];
      const int ecol = (kk * 32 + fq * 8) ^ esw;
#pragma unroll
      for (int m = 0; m < MR; ++m)
        af[m] = *(const bf16x8*)&As[wr * 32 + m * 16 + fr][ecol];
#pragma unroll
      for (int n = 0; n < NR; ++n)
        bfr[n] = *(const bf16x8*)&Bs[wc * 32 + n * 16 + fr][ecol];
#pragma unroll
      for (int m = 0; m < MR; ++m)
#pragma unroll
        for (int n = 0; n < NR; ++n)
          acc[m][n] = __builtin_amdgcn_mfma_f32_16x16x32_bf16(
              af[m], bfr[n], acc[m][n], 0, 0, 0);
    }
    __syncthreads();
  }

#pragma unroll
  for (int n = 0; n < NR; ++n) {
    const int gcol = wc * 32 + n * 16 + fr;
    const float bv = bias[gcol] + t * wtime[gcol];
#pragma unroll
    for (int m = 0; m < MR; ++m) {
      const int grow0 = bm + wr * 32 + m * 16 + (fq << 2);
#pragma unroll
      for (int r = 0; r < 4; ++r) {
        const float kv = acc[m][n][r] + bv;
        const size_t o = (size_t)(grow0 + r) * 64 + gcol;
        if (mode == 0) {
          accb[o] = kv;
          ybf[o] = (bf16_t)(y[o] + cs * kv);
        } else if (mode == 1) {
          accb[o] += ca * kv;
          ybf[o] = (bf16_t)(y[o] + cs * kv);
        } else {
          const float ny = y[o] + cs * (accb[o] + kv);
          y[o] = ny;
          ybf[o] = (bf16_t)ny;
        }
      }
    }
  }
}

// ---------------------------------------------------------------------------
__global__ void prep_weight(const float* __restrict__ W, const float* __restrict__ b,
                            bf16_t* __restrict__ WT, float* __restrict__ bias,
                            float* __restrict__ wtime,
                            int K, int N, int Kpad, int Npad)
{
  int idx = blockIdx.x * 256 + threadIdx.x;
  int total = Npad * Kpad;
  if (idx < total) {
    int n = idx / Kpad, k = idx % Kpad;
    float v = (n < N && k < K) ? W[(size_t)k * N + n] : 0.0f;
    WT[idx] = (bf16_t)v;
  }
  if (idx < Npad) {
    bias[idx]  = (idx < N) ? b[idx] : 0.0f;
    wtime[idx] = (idx < N) ? W[(size_t)K * N + idx] : 0.0f;
  }
}

__global__ void init_y(const float* __restrict__ x, float* __restrict__ y,
                       bf16_t* __restrict__ ybf, int M)
{
  int i = blockIdx.x * 256 + threadIdx.x;
  if (i < M * 64) {
    int m = i >> 6, c = i & 63;
    float v = (c < 2) ? x[m * 2 + c] : 0.0f;
    y[i] = v;
    ybf[i] = (bf16_t)v;
  }
}

__global__ void extract_out(const float* __restrict__ y, float* __restrict__ out, int M)
{
  int i = blockIdx.x * 256 + threadIdx.x;
  if (i < M * 3) {
    int m = i / 3, c = i % 3;
    out[i] = y[(size_t)m * 64 + c];
  }
}

extern "C" void kernel_launch(void* const* d_in, const int* in_sizes, int n_in,
                              void* d_out, int out_size, void* d_ws, size_t ws_size,
                              hipStream_t stream)
{
  (void)in_sizes; (void)n_in; (void)out_size; (void)ws_size;
  const int M = 32768;

  const float* x = (const float*)d_in[0];
  const float* Wp[5]; const float* bp[5];
  for (int i = 0; i < 5; ++i) {
    Wp[i] = (const float*)d_in[1 + 2 * i];
    bp[i] = (const float*)d_in[2 + 2 * i];
  }

  char* ws = (char*)d_ws; size_t off = 0;
  auto alloc = [&](size_t bytes) -> char* {
    char* p = ws + off; off += (bytes + 255) & ~(size_t)255; return p;
  };

  bf16_t* WT[5];
  WT[0] = (bf16_t*)alloc((size_t)1024 * 64 * 2);
  WT[1] = (bf16_t*)alloc((size_t)1024 * 1024 * 2);
  WT[2] = (bf16_t*)alloc((size_t)1024 * 1024 * 2);
  WT[3] = (bf16_t*)alloc((size_t)1024 * 1024 * 2);
  WT[4] = (bf16_t*)alloc((size_t)64 * 1024 * 2);
  float* bias[5]; float* wtm[5];
  for (int i = 0; i < 5; ++i) {
    int Np = (i == 4) ? 64 : 1024;
    bias[i] = (float*)alloc((size_t)Np * 4);
    wtm[i]  = (float*)alloc((size_t)Np * 4);
  }
  float*  y    = (float*)alloc((size_t)M * 64 * 4);
  float*  accb = (float*)alloc((size_t)M * 64 * 4);
  bf16_t* ybf  = (bf16_t*)alloc((size_t)M * 64 * 2);
  bf16_t* act0 = (bf16_t*)alloc((size_t)M * 1024 * 2);
  bf16_t* act1 = (bf16_t*)alloc((size_t)M * 1024 * 2);

  const int Kd[5]  = {50, 1024, 1024, 1024, 1024};
  const int Nd[5]  = {1024, 1024, 1024, 1024, 50};
  const int Kpd[5] = {64, 1024, 1024, 1024, 1024};
  const int Npd[5] = {1024, 1024, 1024, 1024, 64};
  for (int i = 0; i < 5; ++i) {
    int tot = Npd[i] * Kpd[i];
    prep_weight<<<dim3((tot + 255) / 256), 256, 0, stream>>>(
        Wp[i], bp[i], WT[i], bias[i], wtm[i], Kd[i], Nd[i], Kpd[i], Npd[i]);
  }

  init_y<<<dim3((M * 64 + 255) / 256), 256, 0, stream>>>(x, y, ybf, M);

  const float dtv = 1.0f / 32.0f;
  dim3 gL0(M / 128, 1024 / 128);        // 2048 blocks
  dim3 g256(M / 256 * (1024 / 256));    // 512 blocks, %8 == 0
  dim3 gL4(M / 64);                     // 512 blocks = 2/CU

  auto run_net = [&](float t, float ca, float cs, int mode) {
    gemm_bt<128,128,64,2,2,true,true><<<gL0, 256, 0, stream>>>(
        ybf, 64, WT[0], bias[0], wtm[0], t, act0, 1024, M, 64);
    gemm256<1024><<<g256, 512, 0, stream>>>(
        act0, WT[1], bias[1], wtm[1], t, act1, 1024, M, 1024);
    gemm256<1024><<<g256, 512, 0, stream>>>(
        act1, WT[2], bias[2], wtm[2], t, act0, 1024, M, 1024);
    gemm256<1024><<<g256, 512, 0, stream>>>(
        act0, WT[3], bias[3], wtm[3], t, act1, 1024, M, 1024);
    gemm_l4_rk4<<<gL4, 256, 0, stream>>>(
        act1, 1024, WT[4], bias[4], wtm[4], t,
        y, accb, ybf, ca, cs, mode, M, 1024);
  };

  for (int i = 0; i < 32; ++i) {
    const float t0 = i * dtv;
    const float tm = t0 + 0.5f * dtv;
    const float t1 = t0 + dtv;
    run_net(t0, 0.0f, 0.5f * dtv, 0);   // k1
    run_net(tm, 2.0f, 0.5f * dtv, 1);   // k2
    run_net(tm, 2.0f, dtv,        1);   // k3
    run_net(t1, 0.0f, dtv / 6.0f, 2);   // k4
  }

  extract_out<<<dim3((M * 3 + 255) / 256), 256, 0, stream>>>(y, (float*)d_out, M);
}

// Round 12
// 33688.943 us; speedup vs baseline: 1.2304x; 1.2304x over previous
//
#include <hip/hip_runtime.h>
#include <hip/hip_bf16.h>
#include <stdint.h>

// Neural ODE (RK4, 32 steps) over a 5-layer MLP, B=32768, VAR_DIM=50 (pad 64).
// bf16 MFMA GEMMs (16x16x32), fp32 accum, fp32 state y.
// concat(h,t) @ W == h @ W[:K] + (b + t*W[K]) -> time column folded into bias.
// r11: gemm256 reverted to the r7 structure (best measured: 35.17ms; seven
//      scheduling variants all regressed). Layer 0 fused into the L4+RK4
//      kernel: ybf goes registers->LDS->MFMA, producing act0 for the next
//      eval in-kernel. Kills 127 L0 dispatches + all ybf global traffic.

typedef __bf16 bf16_t;
typedef bf16_t bf16x8 __attribute__((ext_vector_type(8)));
typedef float  f32x4  __attribute__((ext_vector_type(4)));

#define DEVI static __device__ __forceinline__

DEVI void gload_lds16(const bf16_t* gsrc, bf16_t* ldst) {
  __builtin_amdgcn_global_load_lds(
      (const __attribute__((address_space(1))) uint32_t*)gsrc,
      (__attribute__((address_space(3))) uint32_t*)ldst,
      16, 0, 0);
}

// ---------------------------------------------------------------------------
// r7 gemm256 (verbatim): 256x256 tile, BK=64, 8 waves (2Mx4N), dbuf LDS,
// one barrier per K-tile, fragment reads pipelined one quadrant ahead.
// ---------------------------------------------------------------------------
template<int K>
__global__ __launch_bounds__(512, 2) void gemm256(
    const bf16_t* __restrict__ A,
    const bf16_t* __restrict__ BT,
    const float* __restrict__ bias,
    const float* __restrict__ wtime,
    float t,
    bf16_t* __restrict__ C, int ldc,
    int M, int N)
{
  constexpr int NT = K / 64;
  static_assert(NT >= 2, "need >=2 K-tiles");

  __shared__ __align__(16) bf16_t As[2][256][64];
  __shared__ __align__(16) bf16_t Bs[2][256][64];

  const int tid  = threadIdx.x;
  const int wave = tid >> 6;
  const int lane = tid & 63;
  const int wr = wave >> 2;
  const int wc = wave & 3;

  int wg = blockIdx.x;
  {
    const int cpx = gridDim.x >> 3;
    wg = (wg & 7) * cpx + (wg >> 3);
  }
  const int nbn = N >> 8;
  const int bm = (wg / nbn) << 8;
  const int bn = (wg % nbn) << 8;

  const int srow = lane >> 3;
  const int scol = ((lane & 7) << 3) ^ ((lane & 32) >> 1) ^ ((wave & 1) << 5);
  const bf16_t* aS = A  + (size_t)(bm + wave * 8 + srow) * K + scol;
  const bf16_t* bS = BT + (size_t)(bn + wave * 8 + srow) * K + scol;
  bf16_t* aD = &As[0][0][0] + wave * 8 * 64;
  bf16_t* bD = &Bs[0][0][0] + wave * 8 * 64;

  auto stageHalf = [&](int kt, int isB, int h) {
    const int buf = kt & 1;
    const bf16_t* src = (isB ? bS : aS) + (size_t)(h * 128) * K + kt * 64;
    bf16_t*       dst = (isB ? bD : aD) + (buf * 256 + h * 128) * 64;
    gload_lds16(src,                  dst);
    gload_lds16(src + (size_t)64 * K, dst + 64 * 64);
  };
  auto stageTile = [&](int kt) {
    stageHalf(kt, 0, 0); stageHalf(kt, 0, 1);
    stageHalf(kt, 1, 0); stageHalf(kt, 1, 1);
  };

  const int fr = lane & 15;
  const int fq = lane >> 4;
  const int rsw = ((fr & 4) << 3) ^ ((fr & 8) << 3);

  bf16x8 ah0[8], ah1[8];
  bf16x8 bh0[4], bh1[4];
  f32x4  acc[8][4] = {};

  auto lda_into = [&](bf16x8 (&dst)[8], int buf, int mh) {
    const char* base = (const char*)&As[buf][0][0];
#pragma unroll
    for (int m = 0; m < 4; ++m)
#pragma unroll
      for (int kk = 0; kk < 2; ++kk) {
        int r  = wr * 128 + (mh * 4 + m) * 16 + fr;
        int cb = (kk * 64 + fq * 16) ^ rsw;
        dst[m * 2 + kk] = *(const bf16x8*)(base + r * 128 + cb);
      }
  };
  auto ldb_into = [&](bf16x8 (&dst)[4], int buf, int nh) {
    const char* base = (const char*)&Bs[buf][0][0];
#pragma unroll
    for (int n = 0; n < 2; ++n)
#pragma unroll
      for (int kk = 0; kk < 2; ++kk) {
        int r  = wc * 64 + (nh * 2 + n) * 16 + fr;
        int cb = (kk * 64 + fq * 16) ^ rsw;
        dst[n * 2 + kk] = *(const bf16x8*)(base + r * 128 + cb);
      }
  };
  auto mma_quad = [&](bf16x8 (&a)[8], bf16x8 (&b)[4], int mh, int nh) {
    __builtin_amdgcn_s_setprio(1);
#pragma unroll
    for (int m = 0; m < 4; ++m)
#pragma unroll
      for (int n = 0; n < 2; ++n)
#pragma unroll
        for (int kk = 0; kk < 2; ++kk)
          acc[mh * 4 + m][nh * 2 + n] = __builtin_amdgcn_mfma_f32_16x16x32_bf16(
              a[m * 2 + kk], b[n * 2 + kk],
              acc[mh * 4 + m][nh * 2 + n], 0, 0, 0);
    __builtin_amdgcn_s_setprio(0);
  };

  stageTile(0);
  asm volatile("s_waitcnt vmcnt(0)" ::: "memory");
  __builtin_amdgcn_s_barrier();
  lda_into(ah0, 0, 0);
  ldb_into(bh0, 0, 0);

  for (int t2 = 0; t2 < NT; ++t2) {
    const int buf = t2 & 1;
    if (t2 + 1 < NT) stageTile(t2 + 1);
    ldb_into(bh1, buf, 1);
    mma_quad(ah0, bh0, 0, 0);
    lda_into(ah1, buf, 1);
    mma_quad(ah0, bh1, 0, 1);
    mma_quad(ah1, bh0, 1, 0);
    if (t2 + 1 < NT) {
      asm volatile("s_waitcnt vmcnt(0)" ::: "memory");
      __builtin_amdgcn_s_barrier();
      lda_into(ah0, buf ^ 1, 0);
      ldb_into(bh0, buf ^ 1, 0);
    }
    mma_quad(ah1, bh1, 1, 1);
  }

#pragma unroll
  for (int n = 0; n < 4; ++n) {
    const int gcol = bn + wc * 64 + n * 16 + fr;
    const float bv = bias[gcol] + t * wtime[gcol];
#pragma unroll
    for (int m = 0; m < 8; ++m) {
      const int grow0 = bm + wr * 128 + m * 16 + (fq << 2);
#pragma unroll
      for (int r = 0; r < 4; ++r) {
        float v = acc[m][n][r] + bv;
        v = v > 0.0f ? v : 0.0f;
        C[(size_t)(grow0 + r) * ldc + gcol] = (bf16_t)v;
      }
    }
  }
}

// ---------------------------------------------------------------------------
// 128^2 kernel (used once, for the initial L0), bank-spread swizzle.
// ---------------------------------------------------------------------------
template<int BM, int BN, int BK, int WROWS, int WCOLS, bool RELU, bool OUT_BF16>
__global__ __launch_bounds__(256) void gemm_bt(
    const bf16_t* __restrict__ A, int lda,
    const bf16_t* __restrict__ BT,
    const float* __restrict__ bias,
    const float* __restrict__ wtime,
    float t,
    void* __restrict__ Cv, int ldc,
    int M, int K)
{
  static_assert(BK == 64, "swizzle assumes BK=64");
  constexpr int MR  = BM / WROWS / 16;
  constexpr int NR  = BN / WCOLS / 16;
  constexpr int TPR = BK / 8;
  constexpr int RPW = 64 / TPR;
  constexpr int RPL = 4 * RPW;
  static_assert(BM % RPL == 0 && BN % RPL == 0, "tile staging mismatch");

  __shared__ bf16_t As[BM][BK];
  __shared__ bf16_t Bs[BN][BK];

  const int tid  = threadIdx.x;
  const int wave = tid >> 6;
  const int lane = tid & 63;
  const int wr = wave / WCOLS;
  const int wc = wave % WCOLS;
  const int bm = blockIdx.x * BM;
  const int bn = blockIdx.y * BN;
  const int lrow = lane >> 3;
  const int lcol = (((lane & 7) << 3) ^ ((lane & 32) >> 1) ^ ((wave & 1) << 5));

  const int fr = lane & 15;
  const int fq = lane >> 4;
  const int esw = ((fr & 4) << 2) ^ ((fr & 8) << 2);

  f32x4 acc[MR][NR] = {};

  for (int k0 = 0; k0 < K; k0 += BK) {
#pragma unroll
    for (int i = 0; i < BM / RPL; ++i) {
      const int rb = i * RPL + wave * RPW;
      gload_lds16(&A[(size_t)(bm + rb + lrow) * lda + k0 + lcol], &As[rb][0]);
    }
#pragma unroll
    for (int i = 0; i < BN / RPL; ++i) {
      const int rb = i * RPL + wave * RPW;
      gload_lds16(&BT[(size_t)(bn + rb + lrow) * K + k0 + lcol], &Bs[rb][0]);
    }
    __syncthreads();
#pragma unroll
    for (int kk = 0; kk < BK / 32; ++kk) {
      bf16x8 af[MR], bfr[NR];
      const int ecol = (kk * 32 + fq * 8) ^ esw;
#pragma unroll
      for (int m = 0; m < MR; ++m)
        af[m] = *(const bf16x8*)&As[wr * (BM / WROWS) + m * 16 + fr][ecol];
#pragma unroll
      for (int n = 0; n < NR; ++n)
        bfr[n] = *(const bf16x8*)&Bs[wc * (BN / WCOLS) + n * 16 + fr][ecol];
#pragma unroll
      for (int m = 0; m < MR; ++m)
#pragma unroll
        for (int n = 0; n < NR; ++n)
          acc[m][n] = __builtin_amdgcn_mfma_f32_16x16x32_bf16(
              af[m], bfr[n], acc[m][n], 0, 0, 0);
    }
    __syncthreads();
  }

#pragma unroll
  for (int n = 0; n < NR; ++n) {
    const int gcol = bn + wc * (BN / WCOLS) + n * 16 + fr;
    const float bv = bias[gcol] + t * wtime[gcol];
#pragma unroll
    for (int m = 0; m < MR; ++m) {
      const int grow0 = bm + wr * (BM / WROWS) + m * 16 + (fq << 2);
#pragma unroll
      for (int r = 0; r < 4; ++r) {
        float v = acc[m][n][r] + bv;
        if (RELU) v = v > 0.0f ? v : 0.0f;
        if constexpr (OUT_BF16)
          ((bf16_t*)Cv)[(size_t)(grow0 + r) * ldc + gcol] = (bf16_t)v;
        else
          ((float*)Cv)[(size_t)(grow0 + r) * ldc + gcol] = v;
      }
    }
  }
}

// ---------------------------------------------------------------------------
// Fused: layer-4 GEMM (N=64,K=1024) + RK4 combine + layer-0 GEMM for the
// NEXT eval. BM=64, 4 waves (2x2), 512 blocks = 2/CU.
// Combine: mode 0: accb=kv, yb=y+cs*kv; 1: accb+=ca*kv, yb=y+cs*kv;
//          2: y+=cs*(accb+kv), yb=y.  yb -> LDS -> act0 = relu(yb@W0+b0(tn)).
// ---------------------------------------------------------------------------
__global__ __launch_bounds__(256) void gemm_l4_rk4_l0(
    const bf16_t* __restrict__ A, int lda,
    const bf16_t* __restrict__ BT,       // W4T [64][1024]
    const float* __restrict__ bias,
    const float* __restrict__ wtime,
    float t,
    const bf16_t* __restrict__ BT0,      // W0T [1024][64]
    const float* __restrict__ bias0,
    const float* __restrict__ wtime0,
    float tn,
    float* __restrict__ y, float* __restrict__ accb,
    bf16_t* __restrict__ act0,
    float ca, float cs, int mode,
    int M, int K)
{
  constexpr int BM = 64, BN = 64, BK = 64;
  constexpr int MR = 2, NR = 2;

  __shared__ bf16_t As[BM][BK];
  __shared__ bf16_t Bs[BN][BK];
  __shared__ bf16_t Ys[64][72];          // ybf tile, +8 pad (2-way-free banks)

  const int tid  = threadIdx.x;
  const int wave = tid >> 6;
  const int lane = tid & 63;
  const int wr = wave >> 1;
  const int wc = wave & 1;
  const int bm = blockIdx.x * BM;
  const int lrow = lane >> 3;
  const int lcol = (((lane & 7) << 3) ^ ((lane & 32) >> 1) ^ ((wave & 1) << 5));

  const int fr = lane & 15;
  const int fq = lane >> 4;
  const int esw = ((fr & 4) << 2) ^ ((fr & 8) << 2);

  f32x4 acc[MR][NR] = {};

  for (int k0 = 0; k0 < K; k0 += BK) {
#pragma unroll
    for (int i = 0; i < 2; ++i) {
      const int rb = i * 32 + wave * 8;
      gload_lds16(&A[(size_t)(bm + rb + lrow) * lda + k0 + lcol], &As[rb][0]);
    }
#pragma unroll
    for (int i = 0; i < 2; ++i) {
      const int rb = i * 32 + wave * 8;
      gload_lds16(&BT[(size_t)(rb + lrow) * K + k0 + lcol], &Bs[rb][0]);
    }
    __syncthreads();
#pragma unroll
    for (int kk = 0; kk < 2; ++kk) {
      bf16x8 af[MR], bfr[NR];
      const int ecol = (kk * 32 + fq * 8) ^ esw;
#pragma unroll
      for (int m = 0; m < MR; ++m)
        af[m] = *(const bf16x8*)&As[wr * 32 + m * 16 + fr][ecol];
#pragma unroll
      for (int n = 0; n < NR; ++n)
        bfr[n] = *(const bf16x8*)&Bs[wc * 32 + n * 16 + fr][ecol];
#pragma unroll
      for (int m = 0; m < MR; ++m)
#pragma unroll
        for (int n = 0; n < NR; ++n)
          acc[m][n] = __builtin_amdgcn_mfma_f32_16x16x32_bf16(
              af[m], bfr[n], acc[m][n], 0, 0, 0);
    }
    __syncthreads();
  }

  // RK4 combine epilogue: update y/accb in global, ybf -> LDS only.
#pragma unroll
  for (int n = 0; n < NR; ++n) {
    const int gcol = wc * 32 + n * 16 + fr;
    const float bv = bias[gcol] + t * wtime[gcol];
#pragma unroll
    for (int m = 0; m < MR; ++m) {
      const int lr0 = wr * 32 + m * 16 + (fq << 2);
#pragma unroll
      for (int r = 0; r < 4; ++r) {
        const float kv = acc[m][n][r] + bv;
        const size_t o = (size_t)(bm + lr0 + r) * 64 + gcol;
        float yb;
        if (mode == 0) {
          accb[o] = kv;
          yb = y[o] + cs * kv;
        } else if (mode == 1) {
          accb[o] += ca * kv;
          yb = y[o] + cs * kv;
        } else {
          const float ny = y[o] + cs * (accb[o] + kv);
          y[o] = ny;
          yb = ny;
        }
        Ys[lr0 + r][gcol] = (bf16_t)yb;
      }
    }
  }
  __syncthreads();

  // Layer 0 for next eval: act0[bm..bm+64][:] = relu(Ys @ W0T^T + b0 + tn*wt0)
  // Per wave: 256 output cols in 4 groups of 64; B frags double-buffered regs.
  const int colbase = wave * 256;
  bf16x8 af0[4][2];
#pragma unroll
  for (int m2 = 0; m2 < 4; ++m2)
#pragma unroll
    for (int kk = 0; kk < 2; ++kk)
      af0[m2][kk] = *(const bf16x8*)&Ys[m2 * 16 + fr][kk * 32 + fq * 8];

  bf16x8 bfA[4][2], bfB[4][2];
  auto ldb0 = [&](bf16x8 (&d)[4][2], int g) {
#pragma unroll
    for (int n = 0; n < 4; ++n)
#pragma unroll
      for (int kk = 0; kk < 2; ++kk)
        d[n][kk] = *(const bf16x8*)(BT0
            + (size_t)(colbase + g * 64 + n * 16 + fr) * 64 + kk * 32 + fq * 8);
  };
  ldb0(bfA, 0);

#pragma unroll
  for (int g = 0; g < 4; ++g) {
    bf16x8 (&bcur)[4][2]  = (g & 1) ? bfB : bfA;
    bf16x8 (&bnext)[4][2] = (g & 1) ? bfA : bfB;
    if (g + 1 < 4) ldb0(bnext, g + 1);
    f32x4 acc2[4][4] = {};
#pragma unroll
    for (int kk = 0; kk < 2; ++kk)
#pragma unroll
      for (int m2 = 0; m2 < 4; ++m2)
#pragma unroll
        for (int n = 0; n < 4; ++n)
          acc2[m2][n] = __builtin_amdgcn_mfma_f32_16x16x32_bf16(
              af0[m2][kk], bcur[n][kk], acc2[m2][n], 0, 0, 0);
#pragma unroll
    for (int n = 0; n < 4; ++n) {
      const int col = colbase + g * 64 + n * 16 + fr;
      const float bv = bias0[col] + tn * wtime0[col];
#pragma unroll
      for (int m2 = 0; m2 < 4; ++m2) {
        const int row0 = bm + m2 * 16 + (fq << 2);
#pragma unroll
        for (int r = 0; r < 4; ++r) {
          float v = acc2[m2][n][r] + bv;
          v = v > 0.0f ? v : 0.0f;
          act0[(size_t)(row0 + r) * 1024 + col] = (bf16_t)v;
        }
      }
    }
  }
}

// ---------------------------------------------------------------------------
__global__ void prep_weight(const float* __restrict__ W, const float* __restrict__ b,
                            bf16_t* __restrict__ WT, float* __restrict__ bias,
                            float* __restrict__ wtime,
                            int K, int N, int Kpad, int Npad)
{
  int idx = blockIdx.x * 256 + threadIdx.x;
  int total = Npad * Kpad;
  if (idx < total) {
    int n = idx / Kpad, k = idx % Kpad;
    float v = (n < N && k < K) ? W[(size_t)k * N + n] : 0.0f;
    WT[idx] = (bf16_t)v;
  }
  if (idx < Npad) {
    bias[idx]  = (idx < N) ? b[idx] : 0.0f;
    wtime[idx] = (idx < N) ? W[(size_t)K * N + idx] : 0.0f;
  }
}

__global__ void init_y(const float* __restrict__ x, float* __restrict__ y,
                       bf16_t* __restrict__ ybf, int M)
{
  int i = blockIdx.x * 256 + threadIdx.x;
  if (i < M * 64) {
    int m = i >> 6, c = i & 63;
    float v = (c < 2) ? x[m * 2 + c] : 0.0f;
    y[i] = v;
    ybf[i] = (bf16_t)v;
  }
}

__global__ void extract_out(const float* __restrict__ y, float* __restrict__ out, int M)
{
  int i = blockIdx.x * 256 + threadIdx.x;
  if (i < M * 3) {
    int m = i / 3, c = i % 3;
    out[i] = y[(size_t)m * 64 + c];
  }
}

extern "C" void kernel_launch(void* const* d_in, const int* in_sizes, int n_in,
                              void* d_out, int out_size, void* d_ws, size_t ws_size,
                              hipStream_t stream)
{
  (void)in_sizes; (void)n_in; (void)out_size; (void)ws_size;
  const int M = 32768;

  const float* x = (const float*)d_in[0];
  const float* Wp[5]; const float* bp[5];
  for (int i = 0; i < 5; ++i) {
    Wp[i] = (const float*)d_in[1 + 2 * i];
    bp[i] = (const float*)d_in[2 + 2 * i];
  }

  char* ws = (char*)d_ws; size_t off = 0;
  auto alloc = [&](size_t bytes) -> char* {
    char* p = ws + off; off += (bytes + 255) & ~(size_t)255; return p;
  };

  bf16_t* WT[5];
  WT[0] = (bf16_t*)alloc((size_t)1024 * 64 * 2);
  WT[1] = (bf16_t*)alloc((size_t)1024 * 1024 * 2);
  WT[2] = (bf16_t*)alloc((size_t)1024 * 1024 * 2);
  WT[3] = (bf16_t*)alloc((size_t)1024 * 1024 * 2);
  WT[4] = (bf16_t*)alloc((size_t)64 * 1024 * 2);
  float* bias[5]; float* wtm[5];
  for (int i = 0; i < 5; ++i) {
    int Np = (i == 4) ? 64 : 1024;
    bias[i] = (float*)alloc((size_t)Np * 4);
    wtm[i]  = (float*)alloc((size_t)Np * 4);
  }
  float*  y    = (float*)alloc((size_t)M * 64 * 4);
  float*  accb = (float*)alloc((size_t)M * 64 * 4);
  bf16_t* ybf  = (bf16_t*)alloc((size_t)M * 64 * 2);
  bf16_t* act0 = (bf16_t*)alloc((size_t)M * 1024 * 2);
  bf16_t* act1 = (bf16_t*)alloc((size_t)M * 1024 * 2);

  const int Kd[5]  = {50, 1024, 1024, 1024, 1024};
  const int Nd[5]  = {1024, 1024, 1024, 1024, 50};
  const int Kpd[5] = {64, 1024, 1024, 1024, 1024};
  const int Npd[5] = {1024, 1024, 1024, 1024, 64};
  for (int i = 0; i < 5; ++i) {
    int tot = Npd[i] * Kpd[i];
    prep_weight<<<dim3((tot + 255) / 256), 256, 0, stream>>>(
        Wp[i], bp[i], WT[i], bias[i], wtm[i], Kd[i], Nd[i], Kpd[i], Npd[i]);
  }

  init_y<<<dim3((M * 64 + 255) / 256), 256, 0, stream>>>(x, y, ybf, M);

  const float dtv = 1.0f / 32.0f;
  dim3 gL0(M / 128, 1024 / 128);        // initial L0 only
  dim3 g256(M / 256 * (1024 / 256));    // 512 blocks, %8 == 0
  dim3 gL4(M / 64);                     // 512 blocks = 2/CU

  // initial L0 (eval 0, t=0) from init ybf
  gemm_bt<128,128,64,2,2,true,true><<<gL0, 256, 0, stream>>>(
      ybf, 64, WT[0], bias[0], wtm[0], 0.0f, act0, 1024, M, 64);

  auto run_eval = [&](float t, float tn, float ca, float cs, int mode) {
    gemm256<1024><<<g256, 512, 0, stream>>>(
        act0, WT[1], bias[1], wtm[1], t, act1, 1024, M, 1024);
    gemm256<1024><<<g256, 512, 0, stream>>>(
        act1, WT[2], bias[2], wtm[2], t, act0, 1024, M, 1024);
    gemm256<1024><<<g256, 512, 0, stream>>>(
        act0, WT[3], bias[3], wtm[3], t, act1, 1024, M, 1024);
    gemm_l4_rk4_l0<<<gL4, 256, 0, stream>>>(
        act1, 1024, WT[4], bias[4], wtm[4], t,
        WT[0], bias[0], wtm[0], tn,
        y, accb, act0, ca, cs, mode, M, 1024);
  };

  for (int i = 0; i < 32; ++i) {
    const float t0 = i * dtv;
    const float tm = t0 + 0.5f * dtv;
    const float t1 = t0 + dtv;
    const float t0n = (i + 1) * dtv;
    run_eval(t0, tm,  0.0f, 0.5f * dtv, 0);   // k1 -> next input at tm
    run_eval(tm, tm,  2.0f, 0.5f * dtv, 1);   // k2 -> next input at tm
    run_eval(tm, t1,  2.0f, dtv,        1);   // k3 -> next input at t1
    run_eval(t1, t0n, 0.0f, dtv / 6.0f, 2);   // k4 -> next step's k1
  }

  extract_out<<<dim3((M * 3 + 255) / 256), 256, 0, stream>>>(y, (float*)d_out, M);
}

// Round 13
// 33630.579 us; speedup vs baseline: 1.2325x; 1.0017x over previous
//
#include <hip/hip_runtime.h>
#include <hip/hip_bf16.h>
#include <stdint.h>

// Neural ODE (RK4, 32 steps) over a 5-layer MLP, B=32768, VAR_DIM=50 (pad 64).
// bf16 MFMA GEMMs (16x16x32), fp32 accum, fp32 state y.
// concat(h,t) @ W == h @ W[:K] + (b + t*W[K]) -> time column folded into bias.
// r12: r11 (33.69ms) with the fused kernel's L4 K-loop converted to the r7
//      pipelined structure (dbuf LDS, stage T+1 at tile top, frag reads one
//      kk ahead, single mid-tile vmcnt(0)+barrier). gemm256 untouched.

typedef __bf16 bf16_t;
typedef bf16_t bf16x8 __attribute__((ext_vector_type(8)));
typedef float  f32x4  __attribute__((ext_vector_type(4)));

#define DEVI static __device__ __forceinline__

DEVI void gload_lds16(const bf16_t* gsrc, bf16_t* ldst) {
  __builtin_amdgcn_global_load_lds(
      (const __attribute__((address_space(1))) uint32_t*)gsrc,
      (__attribute__((address_space(3))) uint32_t*)ldst,
      16, 0, 0);
}

// ---------------------------------------------------------------------------
// r7 gemm256 (verbatim): 256x256 tile, BK=64, 8 waves (2Mx4N), dbuf LDS,
// one barrier per K-tile, fragment reads pipelined one quadrant ahead.
// ---------------------------------------------------------------------------
template<int K>
__global__ __launch_bounds__(512, 2) void gemm256(
    const bf16_t* __restrict__ A,
    const bf16_t* __restrict__ BT,
    const float* __restrict__ bias,
    const float* __restrict__ wtime,
    float t,
    bf16_t* __restrict__ C, int ldc,
    int M, int N)
{
  constexpr int NT = K / 64;
  static_assert(NT >= 2, "need >=2 K-tiles");

  __shared__ __align__(16) bf16_t As[2][256][64];
  __shared__ __align__(16) bf16_t Bs[2][256][64];

  const int tid  = threadIdx.x;
  const int wave = tid >> 6;
  const int lane = tid & 63;
  const int wr = wave >> 2;
  const int wc = wave & 3;

  int wg = blockIdx.x;
  {
    const int cpx = gridDim.x >> 3;
    wg = (wg & 7) * cpx + (wg >> 3);
  }
  const int nbn = N >> 8;
  const int bm = (wg / nbn) << 8;
  const int bn = (wg % nbn) << 8;

  const int srow = lane >> 3;
  const int scol = ((lane & 7) << 3) ^ ((lane & 32) >> 1) ^ ((wave & 1) << 5);
  const bf16_t* aS = A  + (size_t)(bm + wave * 8 + srow) * K + scol;
  const bf16_t* bS = BT + (size_t)(bn + wave * 8 + srow) * K + scol;
  bf16_t* aD = &As[0][0][0] + wave * 8 * 64;
  bf16_t* bD = &Bs[0][0][0] + wave * 8 * 64;

  auto stageHalf = [&](int kt, int isB, int h) {
    const int buf = kt & 1;
    const bf16_t* src = (isB ? bS : aS) + (size_t)(h * 128) * K + kt * 64;
    bf16_t*       dst = (isB ? bD : aD) + (buf * 256 + h * 128) * 64;
    gload_lds16(src,                  dst);
    gload_lds16(src + (size_t)64 * K, dst + 64 * 64);
  };
  auto stageTile = [&](int kt) {
    stageHalf(kt, 0, 0); stageHalf(kt, 0, 1);
    stageHalf(kt, 1, 0); stageHalf(kt, 1, 1);
  };

  const int fr = lane & 15;
  const int fq = lane >> 4;
  const int rsw = ((fr & 4) << 3) ^ ((fr & 8) << 3);

  bf16x8 ah0[8], ah1[8];
  bf16x8 bh0[4], bh1[4];
  f32x4  acc[8][4] = {};

  auto lda_into = [&](bf16x8 (&dst)[8], int buf, int mh) {
    const char* base = (const char*)&As[buf][0][0];
#pragma unroll
    for (int m = 0; m < 4; ++m)
#pragma unroll
      for (int kk = 0; kk < 2; ++kk) {
        int r  = wr * 128 + (mh * 4 + m) * 16 + fr;
        int cb = (kk * 64 + fq * 16) ^ rsw;
        dst[m * 2 + kk] = *(const bf16x8*)(base + r * 128 + cb);
      }
  };
  auto ldb_into = [&](bf16x8 (&dst)[4], int buf, int nh) {
    const char* base = (const char*)&Bs[buf][0][0];
#pragma unroll
    for (int n = 0; n < 2; ++n)
#pragma unroll
      for (int kk = 0; kk < 2; ++kk) {
        int r  = wc * 64 + (nh * 2 + n) * 16 + fr;
        int cb = (kk * 64 + fq * 16) ^ rsw;
        dst[n * 2 + kk] = *(const bf16x8*)(base + r * 128 + cb);
      }
  };
  auto mma_quad = [&](bf16x8 (&a)[8], bf16x8 (&b)[4], int mh, int nh) {
    __builtin_amdgcn_s_setprio(1);
#pragma unroll
    for (int m = 0; m < 4; ++m)
#pragma unroll
      for (int n = 0; n < 2; ++n)
#pragma unroll
        for (int kk = 0; kk < 2; ++kk)
          acc[mh * 4 + m][nh * 2 + n] = __builtin_amdgcn_mfma_f32_16x16x32_bf16(
              a[m * 2 + kk], b[n * 2 + kk],
              acc[mh * 4 + m][nh * 2 + n], 0, 0, 0);
    __builtin_amdgcn_s_setprio(0);
  };

  stageTile(0);
  asm volatile("s_waitcnt vmcnt(0)" ::: "memory");
  __builtin_amdgcn_s_barrier();
  lda_into(ah0, 0, 0);
  ldb_into(bh0, 0, 0);

  for (int t2 = 0; t2 < NT; ++t2) {
    const int buf = t2 & 1;
    if (t2 + 1 < NT) stageTile(t2 + 1);
    ldb_into(bh1, buf, 1);
    mma_quad(ah0, bh0, 0, 0);
    lda_into(ah1, buf, 1);
    mma_quad(ah0, bh1, 0, 1);
    mma_quad(ah1, bh0, 1, 0);
    if (t2 + 1 < NT) {
      asm volatile("s_waitcnt vmcnt(0)" ::: "memory");
      __builtin_amdgcn_s_barrier();
      lda_into(ah0, buf ^ 1, 0);
      ldb_into(bh0, buf ^ 1, 0);
    }
    mma_quad(ah1, bh1, 1, 1);
  }

#pragma unroll
  for (int n = 0; n < 4; ++n) {
    const int gcol = bn + wc * 64 + n * 16 + fr;
    const float bv = bias[gcol] + t * wtime[gcol];
#pragma unroll
    for (int m = 0; m < 8; ++m) {
      const int grow0 = bm + wr * 128 + m * 16 + (fq << 2);
#pragma unroll
      for (int r = 0; r < 4; ++r) {
        float v = acc[m][n][r] + bv;
        v = v > 0.0f ? v : 0.0f;
        C[(size_t)(grow0 + r) * ldc + gcol] = (bf16_t)v;
      }
    }
  }
}

// ---------------------------------------------------------------------------
// 128^2 kernel (used once, for the initial L0), bank-spread swizzle.
// ---------------------------------------------------------------------------
template<int BM, int BN, int BK, int WROWS, int WCOLS, bool RELU, bool OUT_BF16>
__global__ __launch_bounds__(256) void gemm_bt(
    const bf16_t* __restrict__ A, int lda,
    const bf16_t* __restrict__ BT,
    const float* __restrict__ bias,
    const float* __restrict__ wtime,
    float t,
    void* __restrict__ Cv, int ldc,
    int M, int K)
{
  static_assert(BK == 64, "swizzle assumes BK=64");
  constexpr int MR  = BM / WROWS / 16;
  constexpr int NR  = BN / WCOLS / 16;
  constexpr int TPR = BK / 8;
  constexpr int RPW = 64 / TPR;
  constexpr int RPL = 4 * RPW;
  static_assert(BM % RPL == 0 && BN % RPL == 0, "tile staging mismatch");

  __shared__ bf16_t As[BM][BK];
  __shared__ bf16_t Bs[BN][BK];

  const int tid  = threadIdx.x;
  const int wave = tid >> 6;
  const int lane = tid & 63;
  const int wr = wave / WCOLS;
  const int wc = wave % WCOLS;
  const int bm = blockIdx.x * BM;
  const int bn = blockIdx.y * BN;
  const int lrow = lane >> 3;
  const int lcol = (((lane & 7) << 3) ^ ((lane & 32) >> 1) ^ ((wave & 1) << 5));

  const int fr = lane & 15;
  const int fq = lane >> 4;
  const int esw = ((fr & 4) << 2) ^ ((fr & 8) << 2);

  f32x4 acc[MR][NR] = {};

  for (int k0 = 0; k0 < K; k0 += BK) {
#pragma unroll
    for (int i = 0; i < BM / RPL; ++i) {
      const int rb = i * RPL + wave * RPW;
      gload_lds16(&A[(size_t)(bm + rb + lrow) * lda + k0 + lcol], &As[rb][0]);
    }
#pragma unroll
    for (int i = 0; i < BN / RPL; ++i) {
      const int rb = i * RPL + wave * RPW;
      gload_lds16(&BT[(size_t)(bn + rb + lrow) * K + k0 + lcol], &Bs[rb][0]);
    }
    __syncthreads();
#pragma unroll
    for (int kk = 0; kk < BK / 32; ++kk) {
      bf16x8 af[MR], bfr[NR];
      const int ecol = (kk * 32 + fq * 8) ^ esw;
#pragma unroll
      for (int m = 0; m < MR; ++m)
        af[m] = *(const bf16x8*)&As[wr * (BM / WROWS) + m * 16 + fr][ecol];
#pragma unroll
      for (int n = 0; n < NR; ++n)
        bfr[n] = *(const bf16x8*)&Bs[wc * (BN / WCOLS) + n * 16 + fr][ecol];
#pragma unroll
      for (int m = 0; m < MR; ++m)
#pragma unroll
        for (int n = 0; n < NR; ++n)
          acc[m][n] = __builtin_amdgcn_mfma_f32_16x16x32_bf16(
              af[m], bfr[n], acc[m][n], 0, 0, 0);
    }
    __syncthreads();
  }

#pragma unroll
  for (int n = 0; n < NR; ++n) {
    const int gcol = bn + wc * (BN / WCOLS) + n * 16 + fr;
    const float bv = bias[gcol] + t * wtime[gcol];
#pragma unroll
    for (int m = 0; m < MR; ++m) {
      const int grow0 = bm + wr * (BM / WROWS) + m * 16 + (fq << 2);
#pragma unroll
      for (int r = 0; r < 4; ++r) {
        float v = acc[m][n][r] + bv;
        if (RELU) v = v > 0.0f ? v : 0.0f;
        if constexpr (OUT_BF16)
          ((bf16_t*)Cv)[(size_t)(grow0 + r) * ldc + gcol] = (bf16_t)v;
        else
          ((float*)Cv)[(size_t)(grow0 + r) * ldc + gcol] = v;
      }
    }
  }
}

// ---------------------------------------------------------------------------
// Fused: layer-4 GEMM (N=64,K=1024, r7-pipelined) + RK4 combine + layer-0
// GEMM for the NEXT eval. BM=64, 4 waves (2x2), 512 blocks.
// Combine: mode 0: accb=kv, yb=y+cs*kv; 1: accb+=ca*kv, yb=y+cs*kv;
//          2: y+=cs*(accb+kv), yb=y.  yb -> LDS -> act0 = relu(yb@W0+b0(tn)).
// ---------------------------------------------------------------------------
__global__ __launch_bounds__(256) void gemm_l4_rk4_l0(
    const bf16_t* __restrict__ A, int lda,
    const bf16_t* __restrict__ BT,       // W4T [64][1024]
    const float* __restrict__ bias,
    const float* __restrict__ wtime,
    float t,
    const bf16_t* __restrict__ BT0,      // W0T [1024][64]
    const float* __restrict__ bias0,
    const float* __restrict__ wtime0,
    float tn,
    float* __restrict__ y, float* __restrict__ accb,
    bf16_t* __restrict__ act0,
    float ca, float cs, int mode,
    int M, int K)
{
  constexpr int MR = 2, NR = 2;
  const int NT = K / 64;               // 16

  __shared__ __align__(16) bf16_t As[2][64][64];
  __shared__ __align__(16) bf16_t Bs[2][64][64];
  __shared__ bf16_t Ys[64][72];        // ybf tile, +8 pad

  const int tid  = threadIdx.x;
  const int wave = tid >> 6;
  const int lane = tid & 63;
  const int wr = wave >> 1;
  const int wc = wave & 1;
  const int bm = blockIdx.x * 64;
  const int lrow = lane >> 3;
  const int lcol = (((lane & 7) << 3) ^ ((lane & 32) >> 1) ^ ((wave & 1) << 5));

  // staging sources: rows wave*8+lrow and 32+wave*8+lrow of the 64-row panel
  const bf16_t* aS = A  + (size_t)(bm + wave * 8 + lrow) * lda + lcol;
  const bf16_t* bS = BT + (size_t)(wave * 8 + lrow) * K + lcol;
  bf16_t* aD = &As[0][0][0] + wave * 8 * 64;
  bf16_t* bD = &Bs[0][0][0] + wave * 8 * 64;

  auto stage = [&](int kt) {           // 4 gloads per wave
    const int buf = kt & 1;
    gload_lds16(aS + kt * 64,                      aD + buf * 64 * 64);
    gload_lds16(aS + (size_t)32 * lda + kt * 64,   aD + buf * 64 * 64 + 32 * 64);
    gload_lds16(bS + kt * 64,                      bD + buf * 64 * 64);
    gload_lds16(bS + (size_t)32 * K + kt * 64,     bD + buf * 64 * 64 + 32 * 64);
  };

  const int fr = lane & 15;
  const int fq = lane >> 4;
  const int esw = ((fr & 4) << 2) ^ ((fr & 8) << 2);

  bf16x8 af0[2], af1[2], bf0[2], bf1[2];
  f32x4 acc[MR][NR] = {};

  auto ldaf = [&](bf16x8 (&d)[2], int buf, int kk) {
    const int ecol = (kk * 32 + fq * 8) ^ esw;
#pragma unroll
    for (int m = 0; m < 2; ++m)
      d[m] = *(const bf16x8*)&As[buf][wr * 32 + m * 16 + fr][ecol];
  };
  auto ldbf = [&](bf16x8 (&d)[2], int buf, int kk) {
    const int ecol = (kk * 32 + fq * 8) ^ esw;
#pragma unroll
    for (int n = 0; n < 2; ++n)
      d[n] = *(const bf16x8*)&Bs[buf][wc * 32 + n * 16 + fr][ecol];
  };
  auto mma = [&](bf16x8 (&a)[2], bf16x8 (&b)[2]) {
#pragma unroll
    for (int m = 0; m < 2; ++m)
#pragma unroll
      for (int n = 0; n < 2; ++n)
        acc[m][n] = __builtin_amdgcn_mfma_f32_16x16x32_bf16(
            a[m], b[n], acc[m][n], 0, 0, 0);
  };

  // prologue
  stage(0);
  asm volatile("s_waitcnt vmcnt(0)" ::: "memory");
  __builtin_amdgcn_s_barrier();
  ldaf(af0, 0, 0);
  ldbf(bf0, 0, 0);

  for (int t2 = 0; t2 < NT; ++t2) {
    const int buf = t2 & 1;
    if (t2 + 1 < NT) stage(t2 + 1);
    ldaf(af1, buf, 1);
    ldbf(bf1, buf, 1);
    mma(af0, bf0);                      // kk=0
    if (t2 + 1 < NT) {
      asm volatile("s_waitcnt vmcnt(0)" ::: "memory");
      __builtin_amdgcn_s_barrier();
      ldaf(af0, buf ^ 1, 0);
      ldbf(bf0, buf ^ 1, 0);
    }
    mma(af1, bf1);                      // kk=1
  }

  // RK4 combine epilogue: update y/accb in global, ybf -> LDS only.
#pragma unroll
  for (int n = 0; n < NR; ++n) {
    const int gcol = wc * 32 + n * 16 + fr;
    const float bv = bias[gcol] + t * wtime[gcol];
#pragma unroll
    for (int m = 0; m < MR; ++m) {
      const int lr0 = wr * 32 + m * 16 + (fq << 2);
#pragma unroll
      for (int r = 0; r < 4; ++r) {
        const float kv = acc[m][n][r] + bv;
        const size_t o = (size_t)(bm + lr0 + r) * 64 + gcol;
        float yb;
        if (mode == 0) {
          accb[o] = kv;
          yb = y[o] + cs * kv;
        } else if (mode == 1) {
          accb[o] += ca * kv;
          yb = y[o] + cs * kv;
        } else {
          const float ny = y[o] + cs * (accb[o] + kv);
          y[o] = ny;
          yb = ny;
        }
        Ys[lr0 + r][gcol] = (bf16_t)yb;
      }
    }
  }
  __syncthreads();

  // Layer 0 for next eval: act0[bm..bm+64][:] = relu(Ys @ W0T^T + b0 + tn*wt0)
  const int colbase = wave * 256;
  bf16x8 af0v[4][2];
#pragma unroll
  for (int m2 = 0; m2 < 4; ++m2)
#pragma unroll
    for (int kk = 0; kk < 2; ++kk)
      af0v[m2][kk] = *(const bf16x8*)&Ys[m2 * 16 + fr][kk * 32 + fq * 8];

  bf16x8 bfA[4][2], bfB[4][2];
  auto ldb0 = [&](bf16x8 (&d)[4][2], int g) {
#pragma unroll
    for (int n = 0; n < 4; ++n)
#pragma unroll
      for (int kk = 0; kk < 2; ++kk)
        d[n][kk] = *(const bf16x8*)(BT0
            + (size_t)(colbase + g * 64 + n * 16 + fr) * 64 + kk * 32 + fq * 8);
  };
  ldb0(bfA, 0);

#pragma unroll
  for (int g = 0; g < 4; ++g) {
    bf16x8 (&bcur)[4][2]  = (g & 1) ? bfB : bfA;
    bf16x8 (&bnext)[4][2] = (g & 1) ? bfA : bfB;
    if (g + 1 < 4) ldb0(bnext, g + 1);
    f32x4 acc2[4][4] = {};
#pragma unroll
    for (int kk = 0; kk < 2; ++kk)
#pragma unroll
      for (int m2 = 0; m2 < 4; ++m2)
#pragma unroll
        for (int n = 0; n < 4; ++n)
          acc2[m2][n] = __builtin_amdgcn_mfma_f32_16x16x32_bf16(
              af0v[m2][kk], bcur[n][kk], acc2[m2][n], 0, 0, 0);
#pragma unroll
    for (int n = 0; n < 4; ++n) {
      const int col = colbase + g * 64 + n * 16 + fr;
      const float bv = bias0[col] + tn * wtime0[col];
#pragma unroll
      for (int m2 = 0; m2 < 4; ++m2) {
        const int row0 = bm + m2 * 16 + (fq << 2);
#pragma unroll
        for (int r = 0; r < 4; ++r) {
          float v = acc2[m2][n][r] + bv;
          v = v > 0.0f ? v : 0.0f;
          act0[(size_t)(row0 + r) * 1024 + col] = (bf16_t)v;
        }
      }
    }
  }
}

// ---------------------------------------------------------------------------
__global__ void prep_weight(const float* __restrict__ W, const float* __restrict__ b,
                            bf16_t* __restrict__ WT, float* __restrict__ bias,
                            float* __restrict__ wtime,
                            int K, int N, int Kpad, int Npad)
{
  int idx = blockIdx.x * 256 + threadIdx.x;
  int total = Npad * Kpad;
  if (idx < total) {
    int n = idx / Kpad, k = idx % Kpad;
    float v = (n < N && k < K) ? W[(size_t)k * N + n] : 0.0f;
    WT[idx] = (bf16_t)v;
  }
  if (idx < Npad) {
    bias[idx]  = (idx < N) ? b[idx] : 0.0f;
    wtime[idx] = (idx < N) ? W[(size_t)K * N + idx] : 0.0f;
  }
}

__global__ void init_y(const float* __restrict__ x, float* __restrict__ y,
                       bf16_t* __restrict__ ybf, int M)
{
  int i = blockIdx.x * 256 + threadIdx.x;
  if (i < M * 64) {
    int m = i >> 6, c = i & 63;
    float v = (c < 2) ? x[m * 2 + c] : 0.0f;
    y[i] = v;
    ybf[i] = (bf16_t)v;
  }
}

__global__ void extract_out(const float* __restrict__ y, float* __restrict__ out, int M)
{
  int i = blockIdx.x * 256 + threadIdx.x;
  if (i < M * 3) {
    int m = i / 3, c = i % 3;
    out[i] = y[(size_t)m * 64 + c];
  }
}

extern "C" void kernel_launch(void* const* d_in, const int* in_sizes, int n_in,
                              void* d_out, int out_size, void* d_ws, size_t ws_size,
                              hipStream_t stream)
{
  (void)in_sizes; (void)n_in; (void)out_size; (void)ws_size;
  const int M = 32768;

  const float* x = (const float*)d_in[0];
  const float* Wp[5]; const float* bp[5];
  for (int i = 0; i < 5; ++i) {
    Wp[i] = (const float*)d_in[1 + 2 * i];
    bp[i] = (const float*)d_in[2 + 2 * i];
  }

  char* ws = (char*)d_ws; size_t off = 0;
  auto alloc = [&](size_t bytes) -> char* {
    char* p = ws + off; off += (bytes + 255) & ~(size_t)255; return p;
  };

  bf16_t* WT[5];
  WT[0] = (bf16_t*)alloc((size_t)1024 * 64 * 2);
  WT[1] = (bf16_t*)alloc((size_t)1024 * 1024 * 2);
  WT[2] = (bf16_t*)alloc((size_t)1024 * 1024 * 2);
  WT[3] = (bf16_t*)alloc((size_t)1024 * 1024 * 2);
  WT[4] = (bf16_t*)alloc((size_t)64 * 1024 * 2);
  float* bias[5]; float* wtm[5];
  for (int i = 0; i < 5; ++i) {
    int Np = (i == 4) ? 64 : 1024;
    bias[i] = (float*)alloc((size_t)Np * 4);
    wtm[i]  = (float*)alloc((size_t)Np * 4);
  }
  float*  y    = (float*)alloc((size_t)M * 64 * 4);
  float*  accb = (float*)alloc((size_t)M * 64 * 4);
  bf16_t* ybf  = (bf16_t*)alloc((size_t)M * 64 * 2);
  bf16_t* act0 = (bf16_t*)alloc((size_t)M * 1024 * 2);
  bf16_t* act1 = (bf16_t*)alloc((size_t)M * 1024 * 2);

  const int Kd[5]  = {50, 1024, 1024, 1024, 1024};
  const int Nd[5]  = {1024, 1024, 1024, 1024, 50};
  const int Kpd[5] = {64, 1024, 1024, 1024, 1024};
  const int Npd[5] = {1024, 1024, 1024, 1024, 64};
  for (int i = 0; i < 5; ++i) {
    int tot = Npd[i] * Kpd[i];
    prep_weight<<<dim3((tot + 255) / 256), 256, 0, stream>>>(
        Wp[i], bp[i], WT[i], bias[i], wtm[i], Kd[i], Nd[i], Kpd[i], Npd[i]);
  }

  init_y<<<dim3((M * 64 + 255) / 256), 256, 0, stream>>>(x, y, ybf, M);

  const float dtv = 1.0f / 32.0f;
  dim3 gL0(M / 128, 1024 / 128);        // initial L0 only
  dim3 g256(M / 256 * (1024 / 256));    // 512 blocks, %8 == 0
  dim3 gL4(M / 64);                     // 512 blocks

  // initial L0 (eval 0, t=0) from init ybf
  gemm_bt<128,128,64,2,2,true,true><<<gL0, 256, 0, stream>>>(
      ybf, 64, WT[0], bias[0], wtm[0], 0.0f, act0, 1024, M, 64);

  auto run_eval = [&](float t, float tn, float ca, float cs, int mode) {
    gemm256<1024><<<g256, 512, 0, stream>>>(
        act0, WT[1], bias[1], wtm[1], t, act1, 1024, M, 1024);
    gemm256<1024><<<g256, 512, 0, stream>>>(
        act1, WT[2], bias[2], wtm[2], t, act0, 1024, M, 1024);
    gemm256<1024><<<g256, 512, 0, stream>>>(
        act0, WT[3], bias[3], wtm[3], t, act1, 1024, M, 1024);
    gemm_l4_rk4_l0<<<gL4, 256, 0, stream>>>(
        act1, 1024, WT[4], bias[4], wtm[4], t,
        WT[0], bias[0], wtm[0], tn,
        y, accb, act0, ca, cs, mode, M, 1024);
  };

  for (int i = 0; i < 32; ++i) {
    const float t0 = i * dtv;
    const float tm = t0 + 0.5f * dtv;
    const float t1 = t0 + dtv;
    const float t0n = (i + 1) * dtv;
    run_eval(t0, tm,  0.0f, 0.5f * dtv, 0);   // k1 -> next input at tm
    run_eval(tm, tm,  2.0f, 0.5f * dtv, 1);   // k2 -> next input at tm
    run_eval(tm, t1,  2.0f, dtv,        1);   // k3 -> next input at t1
    run_eval(t1, t0n, 0.0f, dtv / 6.0f, 2);   // k4 -> next step's k1
  }

  extract_out<<<dim3((M * 3 + 255) / 256), 256, 0, stream>>>(y, (float*)d_out, M);
}